// Round 5
// baseline (391.804 us; speedup 1.0000x reference)
//
#include <hip/hip_runtime.h>

typedef _Float16 f16;
typedef _Float16 half8 __attribute__((ext_vector_type(8)));
typedef _Float16 half4 __attribute__((ext_vector_type(4)));
typedef __fp16 fp16x2 __attribute__((ext_vector_type(2)));
typedef float f32x4 __attribute__((ext_vector_type(4)));

#define NTOK 343
#define NHEADS 12
#define NBATCH 128
#define HD 32
#define KDIM 384
#define QKV_LD 1152
#define LOG2E 1.4426950408889634f

static __device__ __forceinline__ void gload16(const f16* g, f16* l) {
  __builtin_amdgcn_global_load_lds((const __attribute__((address_space(1))) void*)g,
                                   (__attribute__((address_space(3))) void*)l, 16, 0, 0);
}

static __device__ __forceinline__ float fexp2(float x) {
  float r; asm("v_exp_f32 %0, %1" : "=v"(r) : "v"(x)); return r;
}

// ---------------- K0: fp32 -> fp16 convert ----------------
__global__ __launch_bounds__(256) void cvt_f32_f16(const float* __restrict__ src,
                                                   f16* __restrict__ dst, int n4) {
  int stride = gridDim.x * blockDim.x;
  for (int i = blockIdx.x * blockDim.x + threadIdx.x; i < n4; i += stride) {
    float4 v = reinterpret_cast<const float4*>(src)[i];
    half4 h;
    h[0] = (f16)v.x; h[1] = (f16)v.y; h[2] = (f16)v.z; h[3] = (f16)v.w;
    reinterpret_cast<half4*>(dst)[i] = h;
  }
}

// ---------------- K0b: bias pre-permute into MFMA C-fragment order, f32 ----------------
// bperm[h][qt][kvt][wave][lane][16] f32; elem nt*4+r = bias(q=qt*64+wave*16+(lane&15),
// kv=kvt*64+nt*16+(lane>>4)*4+r) * log2e; kv>=343 -> -30000 (mask baked in).
__global__ __launch_bounds__(256) void bperm_gen(const float* __restrict__ table,
                                                 const int* __restrict__ rel,
                                                 float* __restrict__ out) {
  const int qt = blockIdx.x / 6, kvt = blockIdx.x % 6, h = blockIdx.y;
  const int wave = threadIdx.x >> 6, lane = threadIdx.x & 63;
  const int qi = lane & 15, G = lane >> 4;
  int q = qt*64 + wave*16 + qi; int qc = q < NTOK ? q : NTOK - 1;
  float vals[16];
  #pragma unroll
  for (int nt = 0; nt < 4; ++nt)
    #pragma unroll
    for (int r = 0; r < 4; ++r) {
      int kv = kvt*64 + nt*16 + G*4 + r;
      vals[nt*4+r] = (kv < NTOK) ? table[rel[qc*NTOK + kv]*NHEADS + h] * LOG2E : -30000.0f;
    }
  float* dst = out + ((((size_t)h*6 + qt)*6 + kvt)*4 + wave)*1024 + lane*16;
  #pragma unroll
  for (int c = 0; c < 4; ++c)
    *reinterpret_cast<float4*>(dst + c*4) = *reinterpret_cast<float4*>(&vals[c*4]);
}

// ---------------- 128x128 GEMM body (global_load_lds staging, linear LDS) ----------------
__device__ __forceinline__ void gemm128_body(const f16* __restrict__ A,
                                             const f16* __restrict__ Bw,
                                             int mtile, int ntile,
                                             f32x4 acc[4][4],
                                             f16* As, f16* Bs) {
  const int tid = threadIdx.x;
  const int lane = tid & 63;
  const int w = tid >> 6;
  const int wm = w >> 1, wn = w & 1;

  #pragma unroll
  for (int i = 0; i < 4; ++i)
    #pragma unroll
    for (int j = 0; j < 4; ++j) { f32x4 z = {0.f,0.f,0.f,0.f}; acc[i][j] = z; }

  const int lrow = w * 8 + (lane >> 3);
  const int lcol = (lane & 7) * 8;
  const f16* Ab = A + (size_t)(mtile*128 + lrow) * KDIM + lcol;
  const f16* Bb = Bw + (size_t)(ntile*128 + lrow) * KDIM + lcol;

  for (int k0 = 0; k0 < KDIM; k0 += 64) {
    __syncthreads();
    #pragma unroll
    for (int rnd = 0; rnd < 4; ++rnd) {
      gload16(Ab + (size_t)rnd*32*KDIM + k0, As + rnd*2048 + w*512);
      gload16(Bb + (size_t)rnd*32*KDIM + k0, Bs + rnd*2048 + w*512);
    }
    __syncthreads();
    #pragma unroll
    for (int kk = 0; kk < 2; ++kk) {
      half8 af[4], bf[4];
      #pragma unroll
      for (int mi = 0; mi < 4; ++mi)
        af[mi] = *reinterpret_cast<half8*>(&As[(wm*64 + mi*16 + (lane & 15))*64 + kk*32 + (lane >> 4)*8]);
      #pragma unroll
      for (int ni = 0; ni < 4; ++ni)
        bf[ni] = *reinterpret_cast<half8*>(&Bs[(wn*64 + ni*16 + (lane & 15))*64 + kk*32 + (lane >> 4)*8]);
      #pragma unroll
      for (int mi = 0; mi < 4; ++mi)
        #pragma unroll
        for (int ni = 0; ni < 4; ++ni)
          acc[mi][ni] = __builtin_amdgcn_mfma_f32_16x16x32_f16(af[mi], bf[ni], acc[mi][ni], 0, 0, 0);
    }
  }
}

// ---------------- K1: QKV GEMM -> qkvb[m][1152] (q pre-scaled by scale*log2e) ----------------
__global__ __launch_bounds__(256) void qkv_gemm(const f16* __restrict__ xb,
                                                const f16* __restrict__ wq,
                                                const float* __restrict__ qkv_b,
                                                f16* __restrict__ qkvb) {
  __shared__ __align__(16) f16 smem[17408];
  f16* As = smem;
  f16* Bs = smem + 8192;
  // bijective XCD swizzle (m204), nwg=3087: q=385,r=7
  int orig = blockIdx.x + 9*blockIdx.y;
  int xcd = orig & 7, off = orig >> 3;
  int wg = (xcd < 7 ? xcd*386 : 2702 + (xcd-7)*385) + off;
  const int ntile = wg % 9, mtile = wg / 9;

  f32x4 acc[4][4];
  gemm128_body(xb, wq, mtile, ntile, acc, As, Bs);

  const int tid = threadIdx.x;
  const int lane = tid & 63;
  const int w = tid >> 6;
  const int wm = w >> 1, wn = w & 1;
  const float scale = (ntile < 3) ? 0.17677669529663687f * LOG2E : 1.0f;

  float bj[4];
  #pragma unroll
  for (int ni = 0; ni < 4; ++ni)
    bj[ni] = qkv_b[ntile*128 + wn*64 + ni*16 + (lane & 15)];

  __syncthreads();
  f16* Cs = smem;
  #pragma unroll
  for (int ni = 0; ni < 4; ++ni) {
    int col = wn*64 + ni*16 + (lane & 15);
    #pragma unroll
    for (int mi = 0; mi < 4; ++mi)
      #pragma unroll
      for (int r = 0; r < 4; ++r) {
        int row = wm*64 + mi*16 + (lane >> 4)*4 + r;
        Cs[row*136 + col] = (f16)((acc[mi][ni][r] + bj[ni]) * scale);
      }
  }
  __syncthreads();
  #pragma unroll
  for (int p = 0; p < 8; ++p) {
    int row = p*16 + (tid >> 4);
    int col = (tid & 15) * 8;
    float4 v = *reinterpret_cast<float4*>(&Cs[row*136 + col]);
    *reinterpret_cast<float4*>(&qkvb[(size_t)(mtile*128 + row)*QKV_LD + ntile*128 + col]) = v;
  }
}

// ---------------- K1b: V transpose ----------------
__global__ __launch_bounds__(256) void vtrans(const f16* __restrict__ qkvb,
                                              f16* __restrict__ vt) {
  __shared__ __align__(16) f16 T[64][40];
  const int tid = threadIdx.x;
  const int nt = blockIdx.x, h = blockIdx.y, b = blockIdx.z;
  {
    int row = tid >> 2, ch = tid & 3;
    int n = nt*64 + row; int nc = n < NTOK ? n : NTOK - 1;
    *reinterpret_cast<float4*>(&T[row][ch*8]) =
        *reinterpret_cast<const float4*>(&qkvb[((size_t)b*NTOK + nc)*QKV_LD + 2*KDIM + h*HD + ch*8]);
  }
  __syncthreads();
  int d = tid >> 3, c2 = tid & 7;
  half8 o;
  #pragma unroll
  for (int e = 0; e < 8; ++e) o[e] = T[c2*8 + e][d];
  *reinterpret_cast<half8*>(&vt[((size_t)(b*NHEADS + h)*HD + d)*KDIM + nt*64 + c2*8]) = o;
}

// ---------------- K2: fused flash attention, swapped-QK^T, static softmax ----------------
// grid flat 9216 = (qt6, h12, b128); 4 waves; lane owns q=lane&15, group G=lane>>4.
__global__ __launch_bounds__(256) void attn_kernel(const f16* __restrict__ qkvb,
                                                   const f16* __restrict__ vt,
                                                   const float* __restrict__ bperm,
                                                   f16* __restrict__ ab) {
  __shared__ __align__(16) f16 Qs[64][40];
  __shared__ __align__(16) f16 Ks[64][40];
  __shared__ __align__(16) f16 Vs[32][72];
  __shared__ __align__(16) f16 PB[4][2][4][144];   // [wave][slice][Gt][16q*8e + pad]
  const int tid = threadIdx.x;
  const int lane = tid & 63;
  const int wave = tid >> 6;
  const int qi = lane & 15;
  const int G = lane >> 4;
  // XCD swizzle (9216 % 8 == 0)
  int orig = blockIdx.x + 6*blockIdx.y + 72*blockIdx.z;
  int wg = (orig & 7) * 1152 + (orig >> 3);
  const int qt = wg % 6;
  const int h  = (wg / 6) % 12;
  const int b  = wg / 72;
  const size_t bh = (size_t)b * NHEADS + h;

  {  // stage Q tile (64 x 32)
    int row = tid >> 2, ch = tid & 3;
    int n = qt*64 + row; n = n < NTOK ? n : NTOK - 1;
    *reinterpret_cast<float4*>(&Qs[row][ch*8]) =
        *reinterpret_cast<const float4*>(&qkvb[((size_t)b*NTOK + n)*QKV_LD + h*HD + ch*8]);
  }
  __syncthreads();
  half8 aq = *reinterpret_cast<half8*>(&Qs[wave*16 + qi][G*8]);   // Q B-frag: n=qi, k=G*8+e

  const float* bp = bperm + ((((size_t)h*6 + qt)*6)*4 + wave)*1024 + lane*16;

  half8 vone;
  #pragma unroll
  for (int e = 0; e < 8; ++e) vone[e] = (f16)1.0f;

  // prefetch tile 0: K/V rows + bias fragments
  const int krow = tid >> 2, kch = tid & 3;
  const int vd = tid >> 3, vch = tid & 7;
  float4 kreg, vreg; f32x4 bb0, bb1, bb2, bb3;
  {
    int n = krow; n = n < NTOK ? n : NTOK - 1;
    kreg = *reinterpret_cast<const float4*>(&qkvb[((size_t)b*NTOK + n)*QKV_LD + KDIM + h*HD + kch*8]);
    vreg = *reinterpret_cast<const float4*>(&vt[(bh*HD + vd)*KDIM + vch*8]);
    bb0 = *reinterpret_cast<const f32x4*>(bp);
    bb1 = *reinterpret_cast<const f32x4*>(bp + 4);
    bb2 = *reinterpret_cast<const f32x4*>(bp + 8);
    bb3 = *reinterpret_cast<const f32x4*>(bp + 12);
  }

  f32x4 o0 = {0.f,0.f,0.f,0.f}, o1 = {0.f,0.f,0.f,0.f}, o2 = {0.f,0.f,0.f,0.f};

  for (int kvt = 0; kvt < 6; ++kvt) {
    __syncthreads();   // all waves done reading Ks/Vs of previous tile
    *reinterpret_cast<float4*>(&Ks[krow][kch*8]) = kreg;
    *reinterpret_cast<float4*>(&Vs[vd][vch*8]) = vreg;
    __syncthreads();   // Ks/Vs ready

    // S^T = K @ Q^T + bias (bias rides the MFMA C operand)
    f32x4 s[4];
    half8 ak0 = *reinterpret_cast<half8*>(&Ks[ 0 + qi][G*8]);
    half8 ak1 = *reinterpret_cast<half8*>(&Ks[16 + qi][G*8]);
    half8 ak2 = *reinterpret_cast<half8*>(&Ks[32 + qi][G*8]);
    half8 ak3 = *reinterpret_cast<half8*>(&Ks[48 + qi][G*8]);
    __builtin_amdgcn_s_setprio(1);
    s[0] = __builtin_amdgcn_mfma_f32_16x16x32_f16(ak0, aq, bb0, 0, 0, 0);
    s[1] = __builtin_amdgcn_mfma_f32_16x16x32_f16(ak1, aq, bb1, 0, 0, 0);
    s[2] = __builtin_amdgcn_mfma_f32_16x16x32_f16(ak2, aq, bb2, 0, 0, 0);
    s[3] = __builtin_amdgcn_mfma_f32_16x16x32_f16(ak3, aq, bb3, 0, 0, 0);
    __builtin_amdgcn_s_setprio(0);

    // prefetch next tile while exp/pack/PV run (bias regs now free)
    if (kvt < 5) {
      int n = (kvt+1)*64 + krow; n = n < NTOK ? n : NTOK - 1;
      kreg = *reinterpret_cast<const float4*>(&qkvb[((size_t)b*NTOK + n)*QKV_LD + KDIM + h*HD + kch*8]);
      vreg = *reinterpret_cast<const float4*>(&vt[(bh*HD + vd)*KDIM + (kvt+1)*64 + vch*8]);
      const float* bn = bp + (kvt+1)*4096;
      bb0 = *reinterpret_cast<const f32x4*>(bn);
      bb1 = *reinterpret_cast<const f32x4*>(bn + 4);
      bb2 = *reinterpret_cast<const f32x4*>(bn + 8);
      bb3 = *reinterpret_cast<const f32x4*>(bn + 12);
    }

    // static softmax: P = exp2(S_l) (masked cols -> exact 0), pack to f16 B-frags
    #pragma unroll
    for (int nt = 0; nt < 4; ++nt) {
      float p0 = fexp2(s[nt][0]);
      float p1 = fexp2(s[nt][1]);
      float p2 = fexp2(s[nt][2]);
      float p3 = fexp2(s[nt][3]);
      fp16x2 ph0 = __builtin_amdgcn_cvt_pkrtz(p0, p1);
      fp16x2 ph1 = __builtin_amdgcn_cvt_pkrtz(p2, p3);
      int Gt = 2*(nt & 1) + (G >> 1);
      int sN = nt >> 1;
      *reinterpret_cast<fp16x2*>(&PB[wave][sN][Gt][qi*8 + (G&1)*4])     = ph0;
      *reinterpret_cast<fp16x2*>(&PB[wave][sN][Gt][qi*8 + (G&1)*4 + 2]) = ph1;
    }

    // PV: O^T[d][q] += V^T[d][kv] * P[q][kv]; row-sum via ones-A MFMA (no shuffles)
    half8 pb0 = *reinterpret_cast<half8*>(&PB[wave][0][G][qi*8]);
    half8 pb1 = *reinterpret_cast<half8*>(&PB[wave][1][G][qi*8]);
    half8 av00 = *reinterpret_cast<half8*>(&Vs[qi][G*8]);
    half8 av01 = *reinterpret_cast<half8*>(&Vs[qi][32 + G*8]);
    half8 av10 = *reinterpret_cast<half8*>(&Vs[16 + qi][G*8]);
    half8 av11 = *reinterpret_cast<half8*>(&Vs[16 + qi][32 + G*8]);
    __builtin_amdgcn_s_setprio(1);
    o0 = __builtin_amdgcn_mfma_f32_16x16x32_f16(av00, pb0, o0, 0, 0, 0);
    o0 = __builtin_amdgcn_mfma_f32_16x16x32_f16(av01, pb1, o0, 0, 0, 0);
    o1 = __builtin_amdgcn_mfma_f32_16x16x32_f16(av10, pb0, o1, 0, 0, 0);
    o1 = __builtin_amdgcn_mfma_f32_16x16x32_f16(av11, pb1, o1, 0, 0, 0);
    o2 = __builtin_amdgcn_mfma_f32_16x16x32_f16(vone, pb0, o2, 0, 0, 0);
    o2 = __builtin_amdgcn_mfma_f32_16x16x32_f16(vone, pb1, o2, 0, 0, 0);
    __builtin_amdgcn_s_setprio(0);
  }

  // epilogue: normalize by o2[0] (= row sum, same for all G), coalesced stores
  float inv = 1.0f / o2[0];
  #pragma unroll
  for (int rr = 0; rr < 2; ++rr) {
    fp16x2 a = __builtin_amdgcn_cvt_pkrtz(o0[2*rr]*inv, o0[2*rr+1]*inv);
    *reinterpret_cast<fp16x2*>(&Qs[wave*16 + qi][G*4 + 2*rr]) = a;
    fp16x2 c = __builtin_amdgcn_cvt_pkrtz(o1[2*rr]*inv, o1[2*rr+1]*inv);
    *reinterpret_cast<fp16x2*>(&Qs[wave*16 + qi][16 + G*4 + 2*rr]) = c;
  }
  {
    int row = lane >> 2, ch = lane & 3;
    int q = qt*64 + wave*16 + row;
    if (q < NTOK) {
      float4 v = *reinterpret_cast<float4*>(&Qs[wave*16 + row][ch*8]);
      *reinterpret_cast<float4*>(&ab[((size_t)b*NTOK + q)*KDIM + h*HD + ch*8]) = v;
    }
  }
}

// ---------------- K3: projection GEMM + bias ----------------
__global__ __launch_bounds__(256) void proj_gemm(const f16* __restrict__ ab,
                                                 const f16* __restrict__ wp,
                                                 const float* __restrict__ proj_b,
                                                 float* __restrict__ out) {
  __shared__ __align__(16) f16 smem[16384];
  f16* As = smem;
  f16* Bs = smem + 8192;
  // swizzle nwg=1029: q=128,r=5
  int orig = blockIdx.x + 3*blockIdx.y;
  int xcd = orig & 7, off = orig >> 3;
  int wg = (xcd < 5 ? xcd*129 : 645 + (xcd-5)*128) + off;
  const int ntile = wg % 3, mtile = wg / 3;

  f32x4 acc[4][4];
  gemm128_body(ab, wp, mtile, ntile, acc, As, Bs);
  const int lane = threadIdx.x & 63;
  const int w = threadIdx.x >> 6;
  const int wm = w >> 1, wn = w & 1;
  #pragma unroll
  for (int ni = 0; ni < 4; ++ni) {
    int j = ntile*128 + wn*64 + ni*16 + (lane & 15);
    float pb = proj_b[j];
    #pragma unroll
    for (int mi = 0; mi < 4; ++mi)
      #pragma unroll
      for (int r = 0; r < 4; ++r) {
        int m = mtile*128 + wm*64 + mi*16 + (lane >> 4)*4 + r;
        out[(size_t)m*KDIM + j] = acc[mi][ni][r] + pb;
      }
  }
}

// ---------------- host ----------------
extern "C" void kernel_launch(void* const* d_in, const int* in_sizes, int n_in,
                              void* d_out, int out_size, void* d_ws, size_t ws_size,
                              hipStream_t stream) {
  const float* x          = (const float*)d_in[0];
  const float* qkv_w      = (const float*)d_in[1];
  const float* qkv_b      = (const float*)d_in[2];
  const float* proj_w     = (const float*)d_in[3];
  const float* proj_b     = (const float*)d_in[4];
  const float* bias_table = (const float*)d_in[5];
  const int*   rel_index  = (const int*)d_in[6];

  const size_t M = (size_t)NBATCH * NTOK;
  char* p = (char*)d_ws;
  auto alloc = [&](size_t bytes) { void* r = (void*)p; p += (bytes + 255) & ~(size_t)255; return r; };
  f16*   xb    = (f16*)alloc(M * KDIM * 2);
  f16*   wq    = (f16*)alloc((size_t)3 * KDIM * KDIM * 2);
  f16*   wp    = (f16*)alloc((size_t)KDIM * KDIM * 2);
  f16*   qkvb  = (f16*)alloc(M * QKV_LD * 2);
  f16*   vt    = (f16*)alloc((size_t)NBATCH*NHEADS*HD*KDIM*2);
  float* bperm = (float*)alloc((size_t)NHEADS*6*6*4*64*16*4);
  f16*   ab    = xb;  // alias: xb dead after qkv_gemm

  cvt_f32_f16<<<4096, 256, 0, stream>>>(x, xb, (int)(M * KDIM / 4));
  cvt_f32_f16<<<432, 256, 0, stream>>>(qkv_w, wq, 3 * KDIM * KDIM / 4);
  cvt_f32_f16<<<144, 256, 0, stream>>>(proj_w, wp, KDIM * KDIM / 4);
  bperm_gen<<<dim3(36, NHEADS), 256, 0, stream>>>(bias_table, rel_index, bperm);
  qkv_gemm<<<dim3(9, 343), 256, 0, stream>>>(xb, wq, qkv_b, qkvb);
  vtrans<<<dim3(6, NHEADS, NBATCH), 256, 0, stream>>>(qkvb, vt);
  attn_kernel<<<dim3(6, NHEADS, NBATCH), 256, 0, stream>>>(qkvb, vt, bperm, ab);
  proj_gemm<<<dim3(3, 343), 256, 0, stream>>>(ab, wp, proj_b, (float*)d_out);
}